// Round 1
// baseline (899.156 us; speedup 1.0000x reference)
//
#include <hip/hip_runtime.h>
#include <cstddef>

#ifndef __has_builtin
#define __has_builtin(x) 0
#endif

__device__ __forceinline__ float fast_exp2(float x) {
#if __has_builtin(__builtin_amdgcn_exp2f)
  return __builtin_amdgcn_exp2f(x);   // v_exp_f32: 2^x
#else
  return exp2f(x);
#endif
}
__device__ __forceinline__ float fast_log2(float x) {
#if __has_builtin(__builtin_amdgcn_logf)
  return __builtin_amdgcn_logf(x);    // v_log_f32: log2(x)
#else
  return log2f(x);
#endif
}

namespace {
constexpr int Bc = 256, Tc = 1024, Kc = 128;
constexpr float kLog2e = 1.4426950408889634f;
constexpr float kLn2   = 0.6931471805599453f;
}

// One block per batch row. 512 threads: j = tid&127 (output tag), h = tid>>7
// (0..3, K-split over input tags). Thread (j,h) holds E2[i][j] for
// i in [32h, 32h+32) in registers (E2 = 2^(trans*log2e), precomputed once).
// State: p2[j] = 2^(alpha2[j] - alpha2[0]) in LDS; scalar offset M = alpha2[0]
// (base-2 log domain) tracked redundantly on all h==0 threads.
__global__ __launch_bounds__(512, 2) void crf_forward_kernel(
    const float* __restrict__ hs,      // [B,T,K] emissions
    const float* __restrict__ trans,   // [K,K]
    const float* __restrict__ start_t, // [K]
    const float* __restrict__ end_t,   // [K]
    float* __restrict__ out)           // [B]
{
  __shared__ float p2[Kc];        // 2^beta, beta relative to tag 0
  __shared__ float spart[4 * Kc]; // per-h partial sums of the matvec

  const int b = blockIdx.x;
  const int tid = threadIdx.x;
  const int j = tid & (Kc - 1);
  const int h = tid >> 7;
  const float* __restrict__ emis = hs + (size_t)b * Tc * Kc;

  // E2 quarter-column in registers: 32 VGPRs/thread.
  float E2[32];
#pragma unroll
  for (int u = 0; u < 32; ++u)
    E2[u] = fast_exp2(trans[(32 * h + u) * Kc + j] * kLog2e);

  float M = 0.0f;
  float e_ring[4], e0_ring[4];   // emission prefetch ring, slot = (t-1)&3

  if (h == 0) {
    // alpha2_0[j] = (start[j] + emis[0,j]) * log2e, normalized to tag 0.
    float a0j = (start_t[j] + emis[j]) * kLog2e;
    float a00 = (start_t[0] + emis[0]) * kLog2e;
    p2[j] = fast_exp2(a0j - a00);
    M = a00;
#pragma unroll
    for (int d = 0; d < 4; ++d) {        // preload t = 1..4
      e_ring[d]  = emis[(size_t)(1 + d) * Kc + j];
      e0_ring[d] = emis[(size_t)(1 + d) * Kc];
    }
  }
  __syncthreads();

  auto step = [&](int t, int u) {
    // Matvec quarter: s_h[j] = sum_{i in [32h,32h+32)} p2[i] * E2[i][j].
    // p2 reads are wave-uniform float4 -> LDS broadcast, conflict-free.
    float a0 = 0.f, a1 = 0.f, a2 = 0.f, a3 = 0.f;
    const float4* pv = reinterpret_cast<const float4*>(&p2[32 * h]);
#pragma unroll
    for (int k = 0; k < 8; ++k) {
      float4 p = pv[k];
      a0 = fmaf(p.x, E2[4 * k + 0], a0);
      a1 = fmaf(p.y, E2[4 * k + 1], a1);
      a2 = fmaf(p.z, E2[4 * k + 2], a2);
      a3 = fmaf(p.w, E2[4 * k + 3], a3);
    }
    spart[h * Kc + j] = (a0 + a1) + (a2 + a3);
    __syncthreads();
    if (h == 0) {
      float stot = (spart[j] + spart[Kc + j]) + (spart[2 * Kc + j] + spart[3 * Kc + j]);
      // stot at tag 0 via broadcast reads -> r computed redundantly on all
      // h==0 lanes (no serial thread0->broadcast chain).
      float st0  = (spart[0] + spart[Kc]) + (spart[2 * Kc] + spart[3 * Kc]);
      float r = fmaf(e0_ring[u], kLog2e, fast_log2(st0)); // newbeta at tag 0
      M += r;
      // p2_new[j] = stot_j * 2^(e2_j - r)  (log2+exp2 pair folded into 1 exp2)
      p2[j] = stot * fast_exp2(fmaf(e_ring[u], kLog2e, -r));
      // Prefetch emissions 4 steps ahead (register ring; survives barriers).
      int tn = t + 4;
      if (tn > Tc - 1) tn = Tc - 1;
      e_ring[u]  = emis[(size_t)tn * Kc + j];
      e0_ring[u] = emis[(size_t)tn * Kc];
    }
    __syncthreads();
  };

  // Steps t = 1..1020 (255 exact iterations of 4), then tail 1021..1023.
  for (int tb = 1; tb + 3 < Tc; tb += 4) {
#pragma unroll
    for (int u = 0; u < 4; ++u) step(tb + u, u);
  }
  step(Tc - 3, 0);
  step(Tc - 2, 1);
  step(Tc - 1, 2);

  // logZ = ln2 * (M + log2(sum_j p2[j] * 2^(end2[j])))
  if (h == 0) spart[j] = p2[j] * fast_exp2(end_t[j] * kLog2e);
  __syncthreads();
  if (tid == 0) {
    float S = 0.f;
#pragma unroll 8
    for (int jj = 0; jj < Kc; ++jj) S += spart[jj];
    out[b] = (M + fast_log2(S)) * kLn2;
  }
}

extern "C" void kernel_launch(void* const* d_in, const int* in_sizes, int n_in,
                              void* d_out, int out_size, void* d_ws, size_t ws_size,
                              hipStream_t stream) {
  const float* hs    = (const float*)d_in[0];
  const float* trans = (const float*)d_in[1];
  const float* st    = (const float*)d_in[2];
  const float* en    = (const float*)d_in[3];
  crf_forward_kernel<<<dim3(Bc), dim3(512), 0, stream>>>(hs, trans, st, en, (float*)d_out);
}

// Round 2
// 659.527 us; speedup vs baseline: 1.3633x; 1.3633x over previous
//
#include <hip/hip_runtime.h>
#include <cstddef>
#include <cstdint>

#ifndef __has_builtin
#define __has_builtin(x) 0
#endif

__device__ __forceinline__ float fast_exp2(float x) {
#if __has_builtin(__builtin_amdgcn_exp2f)
  return __builtin_amdgcn_exp2f(x);
#else
  return exp2f(x);
#endif
}
__device__ __forceinline__ float fast_log2(float x) {
#if __has_builtin(__builtin_amdgcn_logf)
  return __builtin_amdgcn_logf(x);
#else
  return log2f(x);
#endif
}

// Workgroup barrier WITHOUT the vmcnt(0) drain __syncthreads carries.
// Orders LDS traffic only (lgkmcnt) — global prefetch loads stay in flight.
__device__ __forceinline__ void bar_lds() {
  asm volatile("s_waitcnt lgkmcnt(0)\n\ts_barrier" ::: "memory");
}

namespace {
constexpr int Bc = 256, Tc = 1024, Kc = 128;
constexpr int CH = 32;           // steps per emission chunk
constexpr int NCH = Tc / CH;     // 32 chunks
constexpr float kLog2e = 1.4426950408889634f;
constexpr float kLn2   = 0.6931471805599453f;
}

// One block per batch row; 256 threads: j = tid&127 (output tag),
// h = tid>>7 (2-way K-split; wave-uniform). Thread (j,h) holds
// E2[i][j] = 2^(trans[i][j]*log2e) for i in [64h,64h+64) in 64 VGPRs.
// State: p2[j] = 2^(alpha2[j] - M) in LDS. Rescale each step by the
// exponent of stot[0] (exact power of 2 — integer ops only, no log/exp
// in the recurrence). Emissions staged 32 steps at a time: global->regs
// at chunk start (stays in flight across raw barriers), exp2'd into LDS
// at chunk end.
__global__ __launch_bounds__(256, 1) void crf_forward_kernel(
    const float* __restrict__ hs,      // [B,T,K]
    const float* __restrict__ trans,   // [K,K]
    const float* __restrict__ start_t, // [K]
    const float* __restrict__ end_t,   // [K]
    float* __restrict__ out)           // [B]
{
  __shared__ __align__(16) float p2[Kc];
  __shared__ __align__(16) float spart[2 * Kc];
  __shared__ __align__(16) float eexp[2][CH * Kc];   // 2 x 16 KB double buffer

  const int b = blockIdx.x;
  const int tid = threadIdx.x;
  const int j = tid & (Kc - 1);
  const int h = tid >> 7;
  const float* __restrict__ emis = hs + (size_t)b * Tc * Kc;
  const float4* __restrict__ emis4 = reinterpret_cast<const float4*>(emis);

  // E2 half-column in registers (64 VGPRs).
  float E2[64];
#pragma unroll
  for (int u = 0; u < 64; ++u)
    E2[u] = fast_exp2(trans[(64 * h + u) * Kc + j] * kLog2e);

  // Stage chunk 0 (t = 0..31): load, exp2, write LDS buf 0.
  float4 r[4];
#pragma unroll
  for (int q = 0; q < 4; ++q) r[q] = emis4[q * 256 + tid];
  {
    float4* bw = reinterpret_cast<float4*>(eexp[0]);
#pragma unroll
    for (int q = 0; q < 4; ++q) {
      float4 v = r[q];
      v.x = fast_exp2(v.x * kLog2e); v.y = fast_exp2(v.y * kLog2e);
      v.z = fast_exp2(v.z * kLog2e); v.w = fast_exp2(v.w * kLog2e);
      bw[q * 256 + tid] = v;
    }
  }

  float Mf = 0.f;       // fractional part of the running log2 offset
  int   Mi = 0;         // integer part (exact)
  float pj = 0.f;       // this thread's p2[j] (tid<128 only)
  if (tid < Kc) {
    float a0j = (start_t[j] + emis[j]) * kLog2e;
    float a00 = (start_t[0] + emis[0]) * kLog2e;
    pj = fast_exp2(a0j - a00);
    p2[j] = pj;
    Mf = a00;
  }
  __syncthreads();   // no global loads outstanding here

  for (int c = 0; c < NCH; ++c) {
    // Issue next chunk's loads now; consumed (vmcnt-waited) at chunk end.
    if (c + 1 < NCH) {
#pragma unroll
      for (int q = 0; q < 4; ++q)
        r[q] = emis4[(size_t)(c + 1) * (CH * Kc / 4) + q * 256 + tid];
    }
    const float* __restrict__ eb = eexp[c & 1];
    const int u0 = (c == 0) ? 1 : 0;   // t=0 is the init, not a step
    for (int u = u0; u < CH; ++u) {
      // Prefetch this step's exp-emission (hides LDS latency behind matvec).
      float ee = eb[u * Kc + j];
      // Matvec half: s = sum_{i in [64h,64h+64)} p2[i] * E2[i][j].
      // p2 reads are wave-uniform float4 -> broadcast, conflict-free.
      const float4* pv = reinterpret_cast<const float4*>(&p2[64 * h]);
      float a0 = 0.f, a1 = 0.f, a2 = 0.f, a3 = 0.f;
      float a4 = 0.f, a5 = 0.f, a6 = 0.f, a7 = 0.f;
#pragma unroll
      for (int k = 0; k < 8; ++k) {
        float4 pA = pv[2 * k];
        float4 pB = pv[2 * k + 1];
        a0 = fmaf(pA.x, E2[8 * k + 0], a0);
        a1 = fmaf(pA.y, E2[8 * k + 1], a1);
        a2 = fmaf(pA.z, E2[8 * k + 2], a2);
        a3 = fmaf(pA.w, E2[8 * k + 3], a3);
        a4 = fmaf(pB.x, E2[8 * k + 4], a4);
        a5 = fmaf(pB.y, E2[8 * k + 5], a5);
        a6 = fmaf(pB.z, E2[8 * k + 6], a6);
        a7 = fmaf(pB.w, E2[8 * k + 7], a7);
      }
      spart[h * Kc + j] = ((a0 + a1) + (a2 + a3)) + ((a4 + a5) + (a6 + a7));
      bar_lds();
      if (tid < Kc) {   // wave-uniform predicate (waves 0,1)
        float stot = spart[j] + spart[Kc + j];
        float st0  = spart[0] + spart[Kc];      // broadcast
        uint32_t E = (__float_as_uint(st0) >> 23) & 0xffu;
        Mi += (int)E - 127;
        float scale = __uint_as_float((254u - E) << 23);  // 2^(127-E)
        pj = stot * scale * ee;
        p2[j] = pj;
      }
      bar_lds();
    }
    // Transform + publish next chunk (vmcnt wait lands here, ~12K cyc late).
    if (c + 1 < NCH) {
      float4* bw = reinterpret_cast<float4*>(eexp[(c + 1) & 1]);
#pragma unroll
      for (int q = 0; q < 4; ++q) {
        float4 v = r[q];
        v.x = fast_exp2(v.x * kLog2e); v.y = fast_exp2(v.y * kLog2e);
        v.z = fast_exp2(v.z * kLog2e); v.w = fast_exp2(v.w * kLog2e);
        bw[q * 256 + tid] = v;
      }
      bar_lds();   // publish before next chunk's first step reads ee
    }
  }

  // logZ = ln2 * (Mf + Mi + log2(sum_j p2[j] * 2^(end2[j])))
  if (tid < Kc) spart[j] = pj * fast_exp2(end_t[j] * kLog2e);
  bar_lds();
  if (tid == 0) {
    float S = 0.f;
    const float4* sp4 = reinterpret_cast<const float4*>(spart);
#pragma unroll 8
    for (int k = 0; k < Kc / 4; ++k) {
      float4 v = sp4[k];
      S += ((v.x + v.y) + (v.z + v.w));
    }
    out[b] = (Mf + (float)Mi + fast_log2(S)) * kLn2;
  }
}

extern "C" void kernel_launch(void* const* d_in, const int* in_sizes, int n_in,
                              void* d_out, int out_size, void* d_ws, size_t ws_size,
                              hipStream_t stream) {
  const float* hs    = (const float*)d_in[0];
  const float* trans = (const float*)d_in[1];
  const float* st    = (const float*)d_in[2];
  const float* en    = (const float*)d_in[3];
  crf_forward_kernel<<<dim3(Bc), dim3(256), 0, stream>>>(hs, trans, st, en, (float*)d_out);
}